// Round 8
// baseline (2981.849 us; speedup 1.0000x reference)
//
#include <hip/hip_runtime.h>
#include <hip/hip_fp16.h>
#include <math.h>

#define BB 128
#define TT 512
#define DD 256
#define HH 256
#define NG 1024  // 4*H

typedef _Float16 h2_t __attribute__((ext_vector_type(2)));
typedef _Float16 f16x8 __attribute__((ext_vector_type(8)));
typedef float f32x4 __attribute__((ext_vector_type(4)));

#if __has_builtin(__builtin_amdgcn_fdot2)
__device__ __forceinline__ float fdot2_(h2_t a, h2_t b, float c) {
    return __builtin_amdgcn_fdot2(a, b, c, false);
}
#else
__device__ __forceinline__ float fdot2_(h2_t a, h2_t b, float c) {
    return c + (float)a.x * (float)b.x + (float)a.y * (float)b.y;
}
#endif

__device__ __forceinline__ float sigmoidf_(float x) {
    return 1.0f / (1.0f + __expf(-x));
}
__device__ __forceinline__ float tanhf_(float x) {
    x = fminf(15.0f, fmaxf(-15.0f, x));
    float e = __expf(2.0f * x);
    return (e - 1.0f) / (e + 1.0f);
}
__device__ __forceinline__ void dot4_(float4& acc, uint4 u, h2_t h) {
    acc.x = fdot2_(__builtin_bit_cast(h2_t, u.x), h, acc.x);
    acc.y = fdot2_(__builtin_bit_cast(h2_t, u.y), h, acc.y);
    acc.z = fdot2_(__builtin_bit_cast(h2_t, u.z), h, acc.z);
    acc.w = fdot2_(__builtin_bit_cast(h2_t, u.w), h, acc.w);
}

// Pack: packed col n = j*4+q <-> gate row g = q*256+j  (q: 0=i,1=f,2=g,3=o)
//  Wg16 [n][k] fp16  (GEMM B operand),  Wr16 [n][k] fp16 = W_hh (rec A operand)
//  Wi16/Wh16 fp16 k-pair-major (fallback), bias_p[n] = b_ih[g] + b_hh[g]
__global__ void pack2(const float* __restrict__ W_ih, const float* __restrict__ W_hh,
                      const float* __restrict__ b_ih, const float* __restrict__ b_hh,
                      __half* __restrict__ Wg16, __half* __restrict__ Wr16,
                      __half* __restrict__ Wi16, __half* __restrict__ Wh16,
                      float* __restrict__ bias_p) {
    int idx = blockIdx.x * 256 + threadIdx.x;   // 0..262143
    int n = idx >> 8;
    int k = idx & 255;
    int g = (n & 3) * 256 + (n >> 2);
    float wih = W_ih[g * 256 + k];
    float whh = W_hh[g * 256 + k];
    Wg16[n * 256 + k] = __float2half(wih);
    Wr16[n * 256 + k] = __float2half(whh);
    size_t hidx = ((size_t)(k >> 1) * 1024 + n) * 2 + (k & 1);
    Wi16[hidx] = __float2half(wih);
    Wh16[hidx] = __float2half(whh);
    if (idx < 1024) {
        int gg = (idx & 3) * 256 + (idx >> 2);
        bias_p[idx] = b_ih[gg] + b_hh[gg];
    }
}

// x fp32 -> fp16, 8 elements/thread
__global__ __launch_bounds__(256) void cvt_x(const float* __restrict__ X,
                                             __half* __restrict__ X16) {
    size_t i = ((size_t)blockIdx.x * 256 + threadIdx.x) * 8;
    float4 a = *(const float4*)&X[i];
    float4 b = *(const float4*)&X[i + 4];
    f16x8 v;
    v[0] = (_Float16)a.x; v[1] = (_Float16)a.y; v[2] = (_Float16)a.z; v[3] = (_Float16)a.w;
    v[4] = (_Float16)b.x; v[5] = (_Float16)b.y; v[6] = (_Float16)b.z; v[7] = (_Float16)b.w;
    *(f16x8*)&X16[i] = v;
}

// xg GEMM: block = 64 M-rows x ALL 1024 N (16 n-groups of 64 looped inside,
// A-frags register-resident -> x16 read ONCE from HBM, was 16x through L3).
__global__ __launch_bounds__(256) void xg_gemm_mfma(const __half* __restrict__ X16,
                                                    const __half* __restrict__ Wg16,
                                                    const float* __restrict__ bias_p,
                                                    __half* __restrict__ xg,
                                                    int t0, int lTc, int tcMask) {
    __shared__ __align__(16) __half st[4][16][72];
    int tid = threadIdx.x;
    int w = tid >> 6, lane = tid & 63;
    int row16 = lane & 15, quad = lane >> 4;
    int m0 = blockIdx.x * 64 + w * 16;

    int mrow = m0 + row16;                                   // chunk-local row
    size_t xrow = (size_t)(mrow >> lTc) * 512 + t0 + (mrow & tcMask);
    const __half* aptr = X16 + xrow * 256 + quad * 8;
    f16x8 afrag[8];
#pragma unroll
    for (int kk = 0; kk < 8; ++kk)
        afrag[kk] = *(const f16x8*)(aptr + kk * 32);

    for (int n0g = 0; n0g < 16; ++n0g) {
        int n0 = n0g * 64;
#pragma unroll
        for (int cg = 0; cg < 4; ++cg) {
            int n = n0 + cg * 16 + row16;
            const __half* bptr = Wg16 + (size_t)n * 256 + quad * 8;
            f32x4 acc = {0.0f, 0.0f, 0.0f, 0.0f};
#pragma unroll
            for (int kk = 0; kk < 8; ++kk) {
                f16x8 bfrag = *(const f16x8*)(bptr + kk * 32);
                acc = __builtin_amdgcn_mfma_f32_16x16x32_f16(afrag[kk], bfrag, acc, 0, 0, 0);
            }
            float bias = bias_p[n];
#pragma unroll
            for (int r = 0; r < 4; ++r)
                st[w][quad * 4 + r][cg * 16 + row16] = __float2half(acc[r] + bias);
        }
        __syncthreads();
        int ml = lane >> 2, cq = lane & 3;
        int mout = blockIdx.x * 64 + w * 16 + ml;            // chunk-local row
        const uint4* src = (const uint4*)&st[w][ml][cq * 16];
        uint4 v0 = src[0], v1 = src[1];
        *(uint4*)&xg[(size_t)mout * 1024 + n0 + cq * 16] = v0;
        *(uint4*)&xg[(size_t)mout * 1024 + n0 + cq * 16 + 8] = v1;
        __syncthreads();
    }
}

// Recurrence via MFMA: 32 blocks x 1024 thr, 4 samples/block.
// gates^T = Wr(1024x256) @ h^T(256x16): A = Wr (constant every step -> pure
// L2 stream, 2 MB/XCD/step), B = h from LDS (sample s duplicated in cols
// s,s+4,s+8,s+12 -> broadcast reads). C (verified layout): col=lane&15=sample
// slot, row=quad*4+reg -> lane's 4 acc regs = gates (i,f,g,o) of column
// col=MT*4+quad. Gates hop through LDS so each of 1024 threads finalizes
// exactly one (sample, column); c-state lives in that thread's register.
__global__ __launch_bounds__(1024) void lstm_mf(const __half* __restrict__ xg,
                                                const __half* __restrict__ Wr16,
                                                const int* __restrict__ x_len,
                                                float* __restrict__ out,
                                                __half* __restrict__ h_state,
                                                float* __restrict__ c_state,
                                                int t0, int Tc) {
    __shared__ __align__(16) __half hs[4 * 264];     // [s][k], row stride 264
    __shared__ __align__(16) float gl[4 * 1032];     // [s][col*4+gate], pad 1032
    int tid = threadIdx.x;
    int w = tid >> 6, lane = tid & 63;
    int row16 = lane & 15, quad = lane >> 4;
    int b0 = blockIdx.x * 4;
    // finalize role: one (sample, column) per thread
    int s_f = tid >> 8, c_f = tid & 255;
    int len_f = x_len[b0 + s_f];
    float cst = 0.0f, h_last = 0.0f;
    if (t0 == 0) {
        hs[s_f * 264 + c_f] = __float2half(0.0f);
    } else {
        __half hv = h_state[(b0 + s_f) * 256 + c_f];
        hs[s_f * 264 + c_f] = hv;
        h_last = __half2float(hv);
        cst = c_state[(b0 + s_f) * 256 + c_f];
    }
    // MFMA role: wave w owns M-tiles 4w..4w+3 (gate rows n = 64w..64w+63)
    const __half* Ab = Wr16 + (size_t)(w * 64 + row16) * 256 + quad * 8;
    int bhw = (lane & 3) * 264 + quad * 8;           // B: sample = col&3
    const __half* xgb = xg + (size_t)(b0 + s_f) * Tc * 1024 + 4 * c_f;
    float* outb = out + ((size_t)(b0 + s_f) * 512 + t0) * 256 + c_f;
    int glw = row16 * 1032;                          // gl row for this sample
    int colb = w * 16 + quad;                        // col = colb + mt*4
    __syncthreads();

    for (int tt = 0; tt < Tc; ++tt) {
        f32x4 a0 = {0.f,0.f,0.f,0.f}, a1 = a0, a2 = a0, a3 = a0;
#pragma unroll
        for (int kk = 0; kk < 8; ++kk) {
            f16x8 bfrag = *(const f16x8*)&hs[bhw + kk * 32];
            f16x8 w0 = *(const f16x8*)(Ab + 0 * 4096 + kk * 32);
            f16x8 w1 = *(const f16x8*)(Ab + 1 * 4096 + kk * 32);
            f16x8 w2 = *(const f16x8*)(Ab + 2 * 4096 + kk * 32);
            f16x8 w3 = *(const f16x8*)(Ab + 3 * 4096 + kk * 32);
            a0 = __builtin_amdgcn_mfma_f32_16x16x32_f16(w0, bfrag, a0, 0, 0, 0);
            a1 = __builtin_amdgcn_mfma_f32_16x16x32_f16(w1, bfrag, a1, 0, 0, 0);
            a2 = __builtin_amdgcn_mfma_f32_16x16x32_f16(w2, bfrag, a2, 0, 0, 0);
            a3 = __builtin_amdgcn_mfma_f32_16x16x32_f16(w3, bfrag, a3, 0, 0, 0);
        }
        if (row16 < 4) {       // real samples only; cols 4-15 are duplicates
            *(float4*)&gl[glw + (colb + 0) * 4] = float4{a0[0], a0[1], a0[2], a0[3]};
            *(float4*)&gl[glw + (colb + 4) * 4] = float4{a1[0], a1[1], a1[2], a1[3]};
            *(float4*)&gl[glw + (colb + 8) * 4] = float4{a2[0], a2[1], a2[2], a2[3]};
            *(float4*)&gl[glw + (colb + 12) * 4] = float4{a3[0], a3[1], a3[2], a3[3]};
        }
        __syncthreads();
        // finalize: this thread's (s_f, c_f)
        uint2 xr = *(const uint2*)(xgb + (size_t)tt * 1024);
        float4 g = *(const float4*)&gl[s_f * 1032 + c_f * 4];
        h2_t x01 = __builtin_bit_cast(h2_t, xr.x);
        h2_t x23 = __builtin_bit_cast(h2_t, xr.y);
        float gi = g.x + (float)x01.x;
        float gf = g.y + (float)x01.y;
        float gg = g.z + (float)x23.x;
        float go = g.w + (float)x23.y;
        float iv = sigmoidf_(gi), fv = sigmoidf_(gf);
        float gv = tanhf_(gg),   ov = sigmoidf_(go);
        cst = fv * cst + iv * gv;
        h_last = ov * tanhf_(cst);
        outb[(size_t)tt * 256] = (t0 + tt < len_f) ? h_last : 0.0f;
        hs[s_f * 264 + c_f] = __float2half(h_last);
        __syncthreads();
    }
    h_state[(b0 + s_f) * 256 + c_f] = __float2half(h_last);
    c_state[(b0 + s_f) * 256 + c_f] = cst;
}

// Fallback (ws too small for any xg chunk): fused, streams both fp16 matrices.
__global__ __launch_bounds__(1024) void lstm_fused16(const float* __restrict__ X,
                                                     const __half* __restrict__ Wi16,
                                                     const __half* __restrict__ Wh16,
                                                     const float* __restrict__ bias_p,
                                                     const int* __restrict__ x_len,
                                                     float* __restrict__ out) {
    __shared__ __half hs_h[256];
    __shared__ __half xs_h[256];
    __shared__ float4 part[3][256];
    int tid = threadIdx.x;
    int c = tid & 255, kh = tid >> 8;
    int b = blockIdx.x;
    int len = x_len[b];
    float cst = 0.0f;
    float4 bias;
    if (kh == 0) {
        bias = *(const float4*)&bias_p[4 * c];
        hs_h[c] = __float2half(0.0f);
    }
    const uint4* wph = (const uint4*)(Wh16 + (size_t)(kh * 32) * 2048 + 8 * c);
    const uint4* wpi = (const uint4*)(Wi16 + (size_t)(kh * 32) * 2048 + 8 * c);
    float* outb = out + (size_t)b * 512 * 256 + c;
    __syncthreads();

    for (int t = 0; t < TT; ++t) {
        if (tid < 128) {
            float2 xv = *(const float2*)&X[((size_t)b * 512 + t) * 256 + 2 * tid];
            h2_t xh = {(_Float16)xv.x, (_Float16)xv.y};
            ((h2_t*)xs_h)[tid] = xh;
        }
        __syncthreads();
        float4 acc = {0.0f, 0.0f, 0.0f, 0.0f};
#pragma unroll 4
        for (int i = 0; i < 32; ++i) {
            uint4 uh = wph[(size_t)i * 256];
            uint4 ui = wpi[(size_t)i * 256];
            h2_t hv = ((const h2_t*)hs_h)[kh * 32 + i];
            h2_t xv = ((const h2_t*)xs_h)[kh * 32 + i];
            dot4_(acc, uh, hv);
            dot4_(acc, ui, xv);
        }
        if (kh) part[kh - 1][c] = acc;
        __syncthreads();
        if (kh == 0) {
            float4 p0 = part[0][c], p1 = part[1][c], p2 = part[2][c];
            float gi = acc.x + p0.x + p1.x + p2.x + bias.x;
            float gf = acc.y + p0.y + p1.y + p2.y + bias.y;
            float gg = acc.z + p0.z + p1.z + p2.z + bias.z;
            float go = acc.w + p0.w + p1.w + p2.w + bias.w;
            float iv = sigmoidf_(gi), fv = sigmoidf_(gf);
            float gv = tanhf_(gg),   ov = sigmoidf_(go);
            cst = fv * cst + iv * gv;
            float h = ov * tanhf_(cst);
            outb[(size_t)t * 256] = (t < len) ? h : 0.0f;
            hs_h[c] = __float2half(h);
        }
        __syncthreads();
    }
}

extern "C" void kernel_launch(void* const* d_in, const int* in_sizes, int n_in,
                              void* d_out, int out_size, void* d_ws, size_t ws_size,
                              hipStream_t stream) {
    const float* x     = (const float*)d_in[0];
    const int*   x_len = (const int*)d_in[1];
    const float* W_ih  = (const float*)d_in[2];
    const float* W_hh  = (const float*)d_in[3];
    const float* b_ih  = (const float*)d_in[4];
    const float* b_hh  = (const float*)d_in[5];
    float* out = (float*)d_out;

    char* ws = (char*)d_ws;
    __half* Wh16    = (__half*)(ws);                      // 512 KB (fallback)
    __half* Wi16    = (__half*)(ws + 0x080000);           // 512 KB (fallback)
    __half* Wg16    = (__half*)(ws + 0x100000);           // 512 KB
    __half* Wr16    = (__half*)(ws + 0x180000);           // 512 KB
    float*  bias_p  = (float*)(ws + 0x200000);            // 4 KB
    __half* h_state = (__half*)(ws + 0x201000);           // 64 KB
    float*  c_state = (float*)(ws + 0x211000);            // 128 KB
    __half* x16     = (__half*)(ws + 0x231000);           // 32 MB
    size_t  o_xg    = 0x231000 + (size_t)0x2000000;
    __half* xg      = (__half*)(ws + o_xg);

    int Tc = 0;
    for (int cand = 512; cand >= 16; cand >>= 1)
        if (ws_size >= o_xg + (size_t)cand * 262144) { Tc = cand; break; }

    pack2<<<1024, 256, 0, stream>>>(W_ih, W_hh, b_ih, b_hh,
                                    Wg16, Wr16, Wi16, Wh16, bias_p);
    if (Tc) {
        cvt_x<<<8192, 256, 0, stream>>>(x, x16);
        int lTc = 31 - __builtin_clz((unsigned)Tc);
        for (int t0 = 0; t0 < TT; t0 += Tc) {
            xg_gemm_mfma<<<2 * Tc, 256, 0, stream>>>(x16, Wg16, bias_p, xg,
                                                     t0, lTc, Tc - 1);
            lstm_mf<<<32, 1024, 0, stream>>>(xg, Wr16, x_len, out,
                                             h_state, c_state, t0, Tc);
        }
    } else {
        lstm_fused16<<<BB, 1024, 0, stream>>>(x, Wi16, Wh16, bias_p, x_len, out);
    }
}